// Round 2
// baseline (713.332 us; speedup 1.0000x reference)
//
#include <hip/hip_runtime.h>
#include <hip/hip_bf16.h>

// ---------------- problem dims ----------------
constexpr int T_ = 2048;   // B*S tokens
constexpr int H_ = 2048;
constexpr int F_ = 1408;
constexpr int E_ = 8;
constexpr int SF_ = 2816;  // shared intermediate

typedef __bf16 bf16;
typedef bf16 bf16x8 __attribute__((ext_vector_type(8)));
typedef float f32x4 __attribute__((ext_vector_type(4)));

#define DEVI __device__ __forceinline__

// async global->LDS, 16B per lane. LDS dest must be wave-uniform base + lane*16.
DEVI void async16(const void* g, void* l) {
    __builtin_amdgcn_global_load_lds(
        (const __attribute__((address_space(1))) unsigned int*)g,
        (__attribute__((address_space(3))) unsigned int*)l, 16, 0, 0);
}

// ---------------- transpose + fp32->bf16 convert ----------------
__global__ void transpose_cvt(const float* __restrict__ src, bf16* __restrict__ dst,
                              int R, int C) {
    int z = blockIdx.z;
    src += (size_t)z * R * C;
    dst += (size_t)z * R * C;
    __shared__ float tile[32][33];
    int tx = threadIdx.x, ty = threadIdx.y;  // 32 x 8
    int c0 = blockIdx.x * 32, r0 = blockIdx.y * 32;
#pragma unroll
    for (int i = 0; i < 4; i++)
        tile[ty + i * 8][tx] = src[(size_t)(r0 + ty + i * 8) * C + c0 + tx];
    __syncthreads();
#pragma unroll
    for (int i = 0; i < 4; i++)
        dst[(size_t)(c0 + ty + i * 8) * R + r0 + tx] = (bf16)tile[tx][ty + i * 8];
}

// ---------------- x fp32 -> bf16 ----------------
__global__ void convert_x(const float* __restrict__ x, bf16* __restrict__ xb) {
    int i = (blockIdx.x * 256 + threadIdx.x) * 8;
    float4 a = *(const float4*)(x + i);
    float4 b = *(const float4*)(x + i + 4);
    bf16x8 v;
    v[0] = (bf16)a.x; v[1] = (bf16)a.y; v[2] = (bf16)a.z; v[3] = (bf16)a.w;
    v[4] = (bf16)b.x; v[5] = (bf16)b.y; v[6] = (bf16)b.z; v[7] = (bf16)b.w;
    *(bf16x8*)(xb + i) = v;
}

// ---------------- gate: softmax + top-2 routing ----------------
__global__ void gate_route(const float* __restrict__ x, const float* __restrict__ gw,
                           int* __restrict__ cnt, int* __restrict__ list,
                           float* __restrict__ wlist) {
    int t = blockIdx.x;
    int tid = threadIdx.x;
    float p[E_];
#pragma unroll
    for (int e = 0; e < E_; e++) p[e] = 0.f;
    const float* xr = x + (size_t)t * H_;
    for (int h = tid; h < H_; h += 256) {
        float xv = xr[h];
#pragma unroll
        for (int e = 0; e < E_; e++) p[e] += xv * gw[e * H_ + h];
    }
#pragma unroll
    for (int e = 0; e < E_; e++)
#pragma unroll
        for (int off = 32; off > 0; off >>= 1) p[e] += __shfl_down(p[e], off, 64);
    __shared__ float wred[4][E_];
    int lane = tid & 63, wid = tid >> 6;
    if (lane == 0)
#pragma unroll
        for (int e = 0; e < E_; e++) wred[wid][e] = p[e];
    __syncthreads();
    if (tid == 0) {
        float l[E_];
#pragma unroll
        for (int e = 0; e < E_; e++) l[e] = wred[0][e] + wred[1][e] + wred[2][e] + wred[3][e];
        float mx = l[0];
#pragma unroll
        for (int e = 1; e < E_; e++) mx = fmaxf(mx, l[e]);
        float sc[E_], s = 0.f;
#pragma unroll
        for (int e = 0; e < E_; e++) { sc[e] = __expf(l[e] - mx); s += sc[e]; }
#pragma unroll
        for (int e = 0; e < E_; e++) sc[e] /= s;
        int i1 = 0;
#pragma unroll
        for (int e = 1; e < E_; e++) if (sc[e] > sc[i1]) i1 = e;
        int i2 = (i1 == 0) ? 1 : 0;
#pragma unroll
        for (int e = 0; e < E_; e++) if (e != i1 && sc[e] > sc[i2]) i2 = e;
        int p1 = atomicAdd(&cnt[i1], 1);
        list[i1 * T_ + p1] = t; wlist[i1 * T_ + p1] = sc[i1];
        int p2 = atomicAdd(&cnt[i2], 1);
        list[i2 * T_ + p2] = t; wlist[i2 * T_ + p2] = sc[i2];
    }
}

// ---------------- gather routed rows (bf16) ----------------
__global__ void gather_rows(const bf16* __restrict__ xb, const int* __restrict__ cnt,
                            const int* __restrict__ list, bf16* __restrict__ xA) {
    int i = blockIdx.x, e = blockIdx.y;
    if (i >= cnt[e]) return;
    int t = list[e * T_ + i];
    const float4* s = (const float4*)(xb + (size_t)t * H_);
    float4* d = (float4*)(xA + ((size_t)e * T_ + i) * H_);
    d[threadIdx.x] = s[threadIdx.x];
}

// ---------------- GEMM: C_act = silu(A@Bg^T) * (A@Bu^T), bf16 out ----------------
// 1-D swizzled grid. EXP mode: e = id&7 (expert -> XCD), col = (id>>3)%ncol,
// rs = (id>>3)/ncol. SHARED mode: col%8 = id&7 (column -> XCD).
// Persistent row loop: rb = rs; rb*128 < M; rb += RS.
template <bool EXP>
__global__ void gemm_dual(const bf16* __restrict__ A, const bf16* __restrict__ Bg,
                          const bf16* __restrict__ Bu, bf16* __restrict__ Cact,
                          const int* __restrict__ cntPtr, int Mfull, int K, int N,
                          long sAe, long sBe, long sCe, int ncol, int ncg, int RS) {
    int id = blockIdx.x;
    int e, col, rs;
    if (EXP) {
        e = id & 7; int r = id >> 3; col = r % ncol; rs = r / ncol;
    } else {
        e = 0; int c8 = id & 7; int r = id >> 3;
        int cg = r % ncg; rs = r / ncg; col = cg * 8 + c8;
        if (col >= ncol) return;
    }
    A += (size_t)e * sAe; Bg += (size_t)e * sBe; Bu += (size_t)e * sBe;
    Cact += (size_t)e * sCe;
    int M = cntPtr ? cntPtr[e] : Mfull;
    int col0 = col * 64;

    __shared__ __align__(16) bf16 As[128 * 64];
    __shared__ __align__(16) bf16 Bgs[64 * 64];
    __shared__ __align__(16) bf16 Bus[64 * 64];

    int tid = threadIdx.x, lane = tid & 63, wid = tid >> 6;
    int wm = (wid >> 1) * 64, wn = (wid & 1) * 32;
    int lm = lane & 15, lq = lane >> 4;
    int nkt = K >> 6;

    for (int rb = rs; rb * 128 < M; rb += RS) {
        int row0 = rb * 128;
        f32x4 accg[4][2] = {};
        f32x4 accu[4][2] = {};

        for (int kt = 0; kt < nkt; kt++) {
            int k0 = kt * 64;
#pragma unroll
            for (int j = 0; j < 4; j++) {          // A tile: 1024 16B chunks
                int L = j * 256 + tid;
                int m = L >> 3, cp = L & 7, c = cp ^ (m & 7);
                int gr = row0 + m; if (gr >= M) gr = M - 1;
                async16(A + (size_t)gr * K + k0 + c * 8, (void*)(As + L * 8));
            }
#pragma unroll
            for (int j = 0; j < 2; j++) {          // Bg/Bu tiles: 512 chunks each
                int L = j * 256 + tid;
                int n = L >> 3, cp = L & 7, c = cp ^ (n & 7);
                async16(Bg + (size_t)(col0 + n) * K + k0 + c * 8, (void*)(Bgs + L * 8));
                async16(Bu + (size_t)(col0 + n) * K + k0 + c * 8, (void*)(Bus + L * 8));
            }
            __syncthreads();
#pragma unroll
            for (int kk = 0; kk < 2; kk++) {
                bf16x8 af[4], bgf[2], buf_[2];
                int cc = kk * 4 + lq;
#pragma unroll
                for (int mi = 0; mi < 4; mi++) {
                    int r = wm + mi * 16 + lm;
                    af[mi] = *(const bf16x8*)(As + r * 64 + ((cc ^ (r & 7)) * 8));
                }
#pragma unroll
                for (int ni = 0; ni < 2; ni++) {
                    int r = wn + ni * 16 + lm;
                    bgf[ni]  = *(const bf16x8*)(Bgs + r * 64 + ((cc ^ (r & 7)) * 8));
                    buf_[ni] = *(const bf16x8*)(Bus + r * 64 + ((cc ^ (r & 7)) * 8));
                }
#pragma unroll
                for (int mi = 0; mi < 4; mi++)
#pragma unroll
                    for (int ni = 0; ni < 2; ni++) {
                        accg[mi][ni] = __builtin_amdgcn_mfma_f32_16x16x32_bf16(af[mi], bgf[ni], accg[mi][ni], 0, 0, 0);
                        accu[mi][ni] = __builtin_amdgcn_mfma_f32_16x16x32_bf16(af[mi], buf_[ni], accu[mi][ni], 0, 0, 0);
                    }
            }
            __syncthreads();
        }
        // epilogue: silu(g)*u -> bf16
#pragma unroll
        for (int mi = 0; mi < 4; mi++)
#pragma unroll
            for (int r = 0; r < 4; r++) {
                int gr = row0 + wm + mi * 16 + lq * 4 + r;
                if (gr >= M) continue;
#pragma unroll
                for (int ni = 0; ni < 2; ni++) {
                    int gc = col0 + wn + ni * 16 + lm;
                    float g = accg[mi][ni][r], u = accu[mi][ni][r];
                    float act = g / (1.f + __expf(-g)) * u;
                    Cact[(size_t)gr * N + gc] = (bf16)act;
                }
            }
    }
}

// ---------------- GEMM: Out = A@Bt^T, fp32 out (write or weighted atomic add) ----
// Same swizzled-grid scheme. BM=128 BN=128 BK=64, 256 thr.
template <bool EXP>
__global__ void gemm_single(const bf16* __restrict__ A, const bf16* __restrict__ Bt,
                            float* __restrict__ Out, const int* __restrict__ cntPtr,
                            int Mfull, int K, int N, const int* __restrict__ list,
                            const float* __restrict__ wlist, long sAe, long sBe,
                            int ncol, int ncg, int RS) {
    int id = blockIdx.x;
    int e, col, rs;
    if (EXP) {
        e = id & 7; int r = id >> 3; col = r % ncol; rs = r / ncol;
    } else {
        e = 0; int c8 = id & 7; int r = id >> 3;
        int cg = r % ncg; rs = r / ncg; col = cg * 8 + c8;
        if (col >= ncol) return;
    }
    A += (size_t)e * sAe; Bt += (size_t)e * sBe;
    const int* lst = list ? list + (size_t)e * T_ : nullptr;
    const float* wl = wlist ? wlist + (size_t)e * T_ : nullptr;
    int M = cntPtr ? cntPtr[e] : Mfull;
    int col0 = col * 128;

    __shared__ __align__(16) bf16 As[128 * 64];
    __shared__ __align__(16) bf16 Bs[128 * 64];

    int tid = threadIdx.x, lane = tid & 63, wid = tid >> 6;
    int wm = (wid >> 1) * 64, wn = (wid & 1) * 64;
    int lm = lane & 15, lq = lane >> 4;
    int nkt = K >> 6;

    for (int rb = rs; rb * 128 < M; rb += RS) {
        int row0 = rb * 128;
        f32x4 acc[4][4] = {};

        for (int kt = 0; kt < nkt; kt++) {
            int k0 = kt * 64;
#pragma unroll
            for (int j = 0; j < 4; j++) {
                int L = j * 256 + tid;
                int m = L >> 3, cp = L & 7, c = cp ^ (m & 7);
                int gr = row0 + m; if (gr >= M) gr = M - 1;
                async16(A + (size_t)gr * K + k0 + c * 8, (void*)(As + L * 8));
                async16(Bt + (size_t)(col0 + m) * K + k0 + c * 8, (void*)(Bs + L * 8));
            }
            __syncthreads();
#pragma unroll
            for (int kk = 0; kk < 2; kk++) {
                bf16x8 af[4], bfr[4];
                int cc = kk * 4 + lq;
#pragma unroll
                for (int i = 0; i < 4; i++) {
                    int ra = wm + i * 16 + lm;
                    af[i] = *(const bf16x8*)(As + ra * 64 + ((cc ^ (ra & 7)) * 8));
                    int rb2 = wn + i * 16 + lm;
                    bfr[i] = *(const bf16x8*)(Bs + rb2 * 64 + ((cc ^ (rb2 & 7)) * 8));
                }
#pragma unroll
                for (int mi = 0; mi < 4; mi++)
#pragma unroll
                    for (int ni = 0; ni < 4; ni++)
                        acc[mi][ni] = __builtin_amdgcn_mfma_f32_16x16x32_bf16(af[mi], bfr[ni], acc[mi][ni], 0, 0, 0);
            }
            __syncthreads();
        }
#pragma unroll
        for (int mi = 0; mi < 4; mi++)
#pragma unroll
            for (int r = 0; r < 4; r++) {
                int cr = row0 + wm + mi * 16 + lq * 4 + r;
                if (cr >= M) continue;
                if (lst) {
                    int t = lst[cr];
                    float w = wl[cr];
#pragma unroll
                    for (int ni = 0; ni < 4; ni++) {
                        int gc = col0 + wn + ni * 16 + lm;
                        atomicAdd(&Out[(size_t)t * N + gc], w * acc[mi][ni][r]);
                    }
                } else {
#pragma unroll
                    for (int ni = 0; ni < 4; ni++) {
                        int gc = col0 + wn + ni * 16 + lm;
                        Out[(size_t)cr * N + gc] = acc[mi][ni][r];
                    }
                }
            }
    }
}

// ---------------- launch ----------------
extern "C" void kernel_launch(void* const* d_in, const int* in_sizes, int n_in,
                              void* d_out, int out_size, void* d_ws, size_t ws_size,
                              hipStream_t stream) {
    const float* x     = (const float*)d_in[0];
    const float* gw    = (const float*)d_in[1];
    const float* gproj = (const float*)d_in[2];
    const float* uproj = (const float*)d_in[3];
    const float* dproj = (const float*)d_in[4];
    const float* sg    = (const float*)d_in[5];
    const float* su    = (const float*)d_in[6];
    const float* sd    = (const float*)d_in[7];
    float* out = (float*)d_out;

    char* w = (char*)d_ws;
    size_t off = 0;
    auto alloc = [&](size_t bytes) { void* p = w + off; off += (bytes + 255) & ~(size_t)255; return p; };
    bf16* wg_t   = (bf16*)alloc((size_t)E_ * F_ * H_ * 2);   // [E][F][H]
    bf16* wu_t   = (bf16*)alloc((size_t)E_ * F_ * H_ * 2);   // [E][F][H]
    bf16* wd_t   = (bf16*)alloc((size_t)E_ * H_ * F_ * 2);   // [E][H][F]
    bf16* sg_t   = (bf16*)alloc((size_t)SF_ * H_ * 2);       // [SF][H]
    bf16* su_t   = (bf16*)alloc((size_t)SF_ * H_ * 2);       // [SF][H]
    bf16* sd_t   = (bf16*)alloc((size_t)H_ * SF_ * 2);       // [H][SF]
    bf16* xb     = (bf16*)alloc((size_t)T_ * H_ * 2);        // [T][H]
    bf16* xA     = (bf16*)alloc((size_t)E_ * T_ * H_ * 2);   // [E][T][H] gathered
    bf16* act    = (bf16*)alloc((size_t)E_ * T_ * F_ * 2);   // [E][T][F]
    bf16* act_sh = (bf16*)alloc((size_t)T_ * SF_ * 2);       // [T][SF]
    int*  cnt    = (int*)alloc(256);
    int*  list   = (int*)alloc((size_t)E_ * T_ * 4);
    float* wlist = (float*)alloc((size_t)E_ * T_ * 4);
    (void)ws_size; (void)in_sizes; (void)n_in; (void)out_size;

    hipMemsetAsync(cnt, 0, 256, stream);

    dim3 tb(32, 8);
    transpose_cvt<<<dim3(F_ / 32, H_ / 32, E_), tb, 0, stream>>>(gproj, wg_t, H_, F_);
    transpose_cvt<<<dim3(F_ / 32, H_ / 32, E_), tb, 0, stream>>>(uproj, wu_t, H_, F_);
    transpose_cvt<<<dim3(H_ / 32, F_ / 32, E_), tb, 0, stream>>>(dproj, wd_t, F_, H_);
    transpose_cvt<<<dim3(SF_ / 32, H_ / 32, 1), tb, 0, stream>>>(sg, sg_t, H_, SF_);
    transpose_cvt<<<dim3(SF_ / 32, H_ / 32, 1), tb, 0, stream>>>(su, su_t, H_, SF_);
    transpose_cvt<<<dim3(H_ / 32, SF_ / 32, 1), tb, 0, stream>>>(sd, sd_t, SF_, H_);

    convert_x<<<T_ * H_ / (256 * 8), 256, 0, stream>>>(x, xb);
    gate_route<<<T_, 256, 0, stream>>>(x, gw, cnt, list, wlist);
    gather_rows<<<dim3(T_, E_), 256, 0, stream>>>(xb, cnt, list, xA);

    // experts gate/up: ncol=F/64=22, RS=4 -> grid 8*22*4=704; expert e -> XCD e
    gemm_dual<true><<<8 * 22 * 4, 256, 0, stream>>>(
        xA, wg_t, wu_t, act, cnt, T_, H_, F_,
        (long)T_ * H_, (long)F_ * H_, (long)T_ * F_, 22, 0, 4);
    // shared gate/up: ncol=SF/64=44, ncg=6 (pad to 48), RS=8 -> grid 8*6*8=384
    gemm_dual<false><<<8 * 6 * 8, 256, 0, stream>>>(
        xb, sg_t, su_t, act_sh, nullptr, T_, H_, SF_, 0, 0, 0, 44, 6, 8);
    // shared down: ncol=H/128=16, ncg=2, RS=16 -> grid 8*2*16=256 (writes out)
    gemm_single<false><<<8 * 2 * 16, 256, 0, stream>>>(
        act_sh, sd_t, out, nullptr, T_, SF_, H_, nullptr, nullptr, 0, 0, 16, 2, 16);
    // experts down: ncol=16, RS=4 -> grid 8*16*4=512 (atomic scatter, out += w*...)
    gemm_single<true><<<8 * 16 * 4, 256, 0, stream>>>(
        act, wd_t, out, cnt, T_, F_, H_, list, wlist,
        (long)T_ * F_, (long)H_ * F_, 16, 0, 4);
}

// Round 3
// 637.059 us; speedup vs baseline: 1.1197x; 1.1197x over previous
//
#include <hip/hip_runtime.h>
#include <hip/hip_bf16.h>

// ---------------- problem dims ----------------
constexpr int T_ = 2048;   // B*S tokens
constexpr int H_ = 2048;
constexpr int F_ = 1408;
constexpr int E_ = 8;
constexpr int SF_ = 2816;  // shared intermediate

typedef __bf16 bf16;
typedef bf16 bf16x8 __attribute__((ext_vector_type(8)));
typedef float f32x4 __attribute__((ext_vector_type(4)));

#define DEVI __device__ __forceinline__

// grid partitions
constexpr int GU_SH = 768;            // shared gate/up part (44 cols padded to 48)
constexpr int GU_EX = 3072;           // expert part (8e x 3colslot x 16rb x 8x)
constexpr int GU_GRID = GU_SH + GU_EX;
constexpr int DN_SH = 512;            // shared down: 16col x 16rb x 2ksplit
constexpr int DN_EX = 2048;           // expert down: 8e x 2colslot x 16rb x 8x
constexpr int DN_GRID = DN_SH + DN_EX;

// async global->LDS, 16B per lane. LDS dest must be wave-uniform base + lane*16.
DEVI void async16(const void* g, void* l) {
    __builtin_amdgcn_global_load_lds(
        (const __attribute__((address_space(1))) unsigned int*)g,
        (__attribute__((address_space(3))) unsigned int*)l, 16, 0, 0);
}

// ---------------- mega transpose: all 6 weight tensors, fp32 [R][C] -> bf16 [C][R]
__global__ void mega_transpose(const float* __restrict__ gp, const float* __restrict__ up,
                               const float* __restrict__ dp, const float* __restrict__ sg,
                               const float* __restrict__ su, const float* __restrict__ sd,
                               bf16* __restrict__ wg, bf16* __restrict__ wu,
                               bf16* __restrict__ wd, bf16* __restrict__ sgt,
                               bf16* __restrict__ sut, bf16* __restrict__ sdt) {
    int id = blockIdx.x;
    const float* src; bf16* dst; int R, C, t;
    if (id < 5632)       { int e = id / 704; t = id % 704; R = 2048; C = 1408;
                           src = gp + (size_t)e * R * C; dst = wg + (size_t)e * R * C; }
    else if (id < 11264) { int e = (id - 5632) / 704; t = (id - 5632) % 704; R = 2048; C = 1408;
                           src = up + (size_t)e * R * C; dst = wu + (size_t)e * R * C; }
    else if (id < 16896) { int e = (id - 11264) / 704; t = (id - 11264) % 704; R = 1408; C = 2048;
                           src = dp + (size_t)e * R * C; dst = wd + (size_t)e * R * C; }
    else if (id < 18304) { t = id - 16896; R = 2048; C = 2816; src = sg; dst = sgt; }
    else if (id < 19712) { t = id - 18304; R = 2048; C = 2816; src = su; dst = sut; }
    else                 { t = id - 19712; R = 2816; C = 2048; src = sd; dst = sdt; }
    int tiles_c = C >> 6;
    int r0 = (t / tiles_c) * 64, c0 = (t % tiles_c) * 64;

    __shared__ float tile[64][68];   // stride 68: 16B-aligned rows
    int th = threadIdx.x;
    int lr = th >> 4, lc4 = (th & 15) * 4;
#pragma unroll
    for (int i = 0; i < 4; i++) {
        int r = lr + i * 16;
        float4 v = *(const float4*)(src + (size_t)(r0 + r) * C + c0 + lc4);
        *(float4*)&tile[r][lc4] = v;
    }
    __syncthreads();
#pragma unroll
    for (int p = 0; p < 2; p++) {
        int ch = th + p * 256;          // 512 chunks: c = ch&63 (lane-major: LDS 2-way free)
        int c = ch & 63, rq = ch >> 6;  // rq 0..7
        bf16x8 o;
#pragma unroll
        for (int j = 0; j < 8; j++) o[j] = (bf16)tile[rq * 8 + j][c];
        *(bf16x8*)(dst + (size_t)(c0 + c) * R + r0 + rq * 8) = o;
    }
}

// ---------------- fused x fp32->bf16 convert + gate softmax + top-2 route ----------
__global__ void gate_cvt_route(const float* __restrict__ x, const float* __restrict__ gw,
                               bf16* __restrict__ xb, int* __restrict__ cnt,
                               int* __restrict__ list, float* __restrict__ wlist) {
    int t = blockIdx.x, tid = threadIdx.x;
    const float* xr = x + (size_t)t * H_;
    int h0 = tid * 8;
    float4 a = *(const float4*)(xr + h0);
    float4 b = *(const float4*)(xr + h0 + 4);
    float xv[8] = {a.x, a.y, a.z, a.w, b.x, b.y, b.z, b.w};
    bf16x8 v;
#pragma unroll
    for (int j = 0; j < 8; j++) v[j] = (bf16)xv[j];
    *(bf16x8*)(xb + (size_t)t * H_ + h0) = v;

    float p[E_];
#pragma unroll
    for (int e = 0; e < E_; e++) p[e] = 0.f;
#pragma unroll
    for (int j = 0; j < 8; j++)
#pragma unroll
        for (int e = 0; e < E_; e++) p[e] += xv[j] * gw[e * H_ + h0 + j];
#pragma unroll
    for (int e = 0; e < E_; e++)
#pragma unroll
        for (int off = 32; off > 0; off >>= 1) p[e] += __shfl_down(p[e], off, 64);
    __shared__ float wred[4][E_];
    int lane = tid & 63, wid = tid >> 6;
    if (lane == 0)
#pragma unroll
        for (int e = 0; e < E_; e++) wred[wid][e] = p[e];
    __syncthreads();
    if (tid == 0) {
        float l[E_];
#pragma unroll
        for (int e = 0; e < E_; e++) l[e] = wred[0][e] + wred[1][e] + wred[2][e] + wred[3][e];
        float mx = l[0];
#pragma unroll
        for (int e = 1; e < E_; e++) mx = fmaxf(mx, l[e]);
        float sc[E_], s = 0.f;
#pragma unroll
        for (int e = 0; e < E_; e++) { sc[e] = __expf(l[e] - mx); s += sc[e]; }
#pragma unroll
        for (int e = 0; e < E_; e++) sc[e] /= s;
        int i1 = 0;
#pragma unroll
        for (int e = 1; e < E_; e++) if (sc[e] > sc[i1]) i1 = e;
        int i2 = (i1 == 0) ? 1 : 0;
#pragma unroll
        for (int e = 0; e < E_; e++) if (e != i1 && sc[e] > sc[i2]) i2 = e;
        int p1 = atomicAdd(&cnt[i1], 1);
        list[i1 * T_ + p1] = t; wlist[i1 * T_ + p1] = sc[i1];
        int p2 = atomicAdd(&cnt[i2], 1);
        list[i2 * T_ + p2] = t; wlist[i2 * T_ + p2] = sc[i2];
    }
}

// ---------------- gather routed rows (bf16) ----------------
__global__ void gather_rows(const bf16* __restrict__ xb, const int* __restrict__ cnt,
                            const int* __restrict__ list, bf16* __restrict__ xA) {
    int i = blockIdx.x, e = blockIdx.y;
    if (i >= cnt[e]) return;
    int t = list[e * T_ + i];
    const float4* s = (const float4*)(xb + (size_t)t * H_);
    float4* d = (float4*)(xA + ((size_t)e * T_ + i) * H_);
    d[threadIdx.x] = s[threadIdx.x];
}

// ---------------- combined gate/up GEMM: act = [w *] silu(A@Bg^T)*(A@Bu^T) --------
// One launch covers shared (M=T,N=SF) and all 8 experts (M=cnt[e],N=F). K=H for all.
// XCD swizzle: id&7 = XCD slot; same (source,col) stays on one XCD.
__global__ void gemm_gu(const bf16* __restrict__ xb, const bf16* __restrict__ xA,
                        const bf16* __restrict__ sgt, const bf16* __restrict__ sut,
                        const bf16* __restrict__ wg, const bf16* __restrict__ wu,
                        bf16* __restrict__ act_sh, bf16* __restrict__ act,
                        const int* __restrict__ cnt, const float* __restrict__ wlist) {
    int id = blockIdx.x;
    const bf16 *A, *Bg, *Bu; bf16* C;
    const float* wl = nullptr;
    int M, N, row0, col0;
    if (id < GU_SH) {
        int x = id & 7, u = id >> 3;            // u in [0,96)
        int cg = u >> 4, rb = u & 15;
        int col = cg * 8 + x;                   // 0..47, valid <44
        if (col >= 44) return;
        A = xb; Bg = sgt; Bu = sut; C = act_sh;
        M = T_; N = SF_; row0 = rb * 128; col0 = col * 64;
    } else {
        int id2 = id - GU_SH;
        int x = id2 & 7, u = id2 >> 3;          // u in [0,384)
        int e = u / 48, t2 = u % 48, j = t2 >> 4, rb = t2 & 15;
        int col = ((x - e) & 7) + 8 * j;        // 0..23, valid <22
        if (col >= 22) return;
        M = cnt[e]; row0 = rb * 128;
        if (row0 >= M) return;
        A = xA + (size_t)e * T_ * H_;
        Bg = wg + (size_t)e * F_ * H_;
        Bu = wu + (size_t)e * F_ * H_;
        C = act + (size_t)e * T_ * F_;
        wl = wlist + (size_t)e * T_;
        N = F_; col0 = col * 64;
    }

    __shared__ __align__(16) bf16 As[128 * 64];
    __shared__ __align__(16) bf16 Bgs[64 * 64];
    __shared__ __align__(16) bf16 Bus[64 * 64];

    int tid = threadIdx.x, lane = tid & 63, wid = tid >> 6;
    int wm = (wid >> 1) * 64, wn = (wid & 1) * 32;
    int lm = lane & 15, lq = lane >> 4;

    f32x4 accg[4][2] = {};
    f32x4 accu[4][2] = {};
    constexpr int nkt = H_ >> 6;   // 32

    for (int kt = 0; kt < nkt; kt++) {
        int k0 = kt * 64;
#pragma unroll
        for (int j = 0; j < 4; j++) {          // A tile: 1024 16B chunks
            int L = j * 256 + tid;
            int m = L >> 3, cp = L & 7, c = cp ^ (m & 7);
            int gr = row0 + m; if (gr >= M) gr = M - 1;
            async16(A + (size_t)gr * H_ + k0 + c * 8, (void*)(As + L * 8));
        }
#pragma unroll
        for (int j = 0; j < 2; j++) {          // Bg/Bu tiles: 512 chunks each
            int L = j * 256 + tid;
            int n = L >> 3, cp = L & 7, c = cp ^ (n & 7);
            async16(Bg + (size_t)(col0 + n) * H_ + k0 + c * 8, (void*)(Bgs + L * 8));
            async16(Bu + (size_t)(col0 + n) * H_ + k0 + c * 8, (void*)(Bus + L * 8));
        }
        __syncthreads();
#pragma unroll
        for (int kk = 0; kk < 2; kk++) {
            bf16x8 af[4], bgf[2], buf_[2];
            int cc = kk * 4 + lq;
#pragma unroll
            for (int mi = 0; mi < 4; mi++) {
                int r = wm + mi * 16 + lm;
                af[mi] = *(const bf16x8*)(As + r * 64 + ((cc ^ (r & 7)) * 8));
            }
#pragma unroll
            for (int ni = 0; ni < 2; ni++) {
                int r = wn + ni * 16 + lm;
                bgf[ni]  = *(const bf16x8*)(Bgs + r * 64 + ((cc ^ (r & 7)) * 8));
                buf_[ni] = *(const bf16x8*)(Bus + r * 64 + ((cc ^ (r & 7)) * 8));
            }
#pragma unroll
            for (int mi = 0; mi < 4; mi++)
#pragma unroll
                for (int ni = 0; ni < 2; ni++) {
                    accg[mi][ni] = __builtin_amdgcn_mfma_f32_16x16x32_bf16(af[mi], bgf[ni], accg[mi][ni], 0, 0, 0);
                    accu[mi][ni] = __builtin_amdgcn_mfma_f32_16x16x32_bf16(af[mi], buf_[ni], accu[mi][ni], 0, 0, 0);
                }
        }
        __syncthreads();
    }
    // epilogue: [w *] silu(g)*u -> bf16
#pragma unroll
    for (int mi = 0; mi < 4; mi++)
#pragma unroll
        for (int r = 0; r < 4; r++) {
            int gr = row0 + wm + mi * 16 + lq * 4 + r;
            if (gr >= M) continue;
            float wv = wl ? wl[gr] : 1.f;
#pragma unroll
            for (int ni = 0; ni < 2; ni++) {
                int gc = col0 + wn + ni * 16 + lm;
                float g = accg[mi][ni][r], u = accu[mi][ni][r];
                float actv = wv * (g / (1.f + __expf(-g)) * u);
                C[(size_t)gr * N + gc] = (bf16)actv;
            }
        }
}

// ---------------- combined down GEMM: out += A@Bt^T (all atomic, out pre-zeroed) --
// Shared part split-K=2 (K half = 1408); expert part K = 1408. N = H for all.
__global__ void gemm_down(const bf16* __restrict__ act_sh, const bf16* __restrict__ sdt,
                          const bf16* __restrict__ act, const bf16* __restrict__ wd,
                          float* __restrict__ out, const int* __restrict__ cnt,
                          const int* __restrict__ list) {
    int id = blockIdx.x;
    const bf16 *A, *B; const int* lst = nullptr;
    int M, KA, kbase, row0, col0;
    if (id < DN_SH) {
        int x = id & 7, u = id >> 3;            // u in [0,64)
        int cg = u >> 5, rest = u & 31, rb = rest >> 1, ks = rest & 1;
        int col = cg * 8 + x;                   // 0..15
        A = act_sh; B = sdt; M = T_; KA = SF_; kbase = ks * 1408;
        row0 = rb * 128; col0 = col * 128;
    } else {
        int id2 = id - DN_SH;
        int x = id2 & 7, u = id2 >> 3;          // u in [0,256)
        int e = u >> 5, t2 = u & 31, j = t2 >> 4, rb = t2 & 15;
        int col = ((x - e) & 7) + 8 * j;        // 0..15
        M = cnt[e]; row0 = rb * 128;
        if (row0 >= M) return;
        A = act + (size_t)e * T_ * F_;
        B = wd + (size_t)e * H_ * F_;
        lst = list + (size_t)e * T_;
        KA = F_; kbase = 0; col0 = col * 128;
    }

    __shared__ __align__(16) bf16 As[128 * 64];
    __shared__ __align__(16) bf16 Bs[128 * 64];

    int tid = threadIdx.x, lane = tid & 63, wid = tid >> 6;
    int wm = (wid >> 1) * 64, wn = (wid & 1) * 64;
    int lm = lane & 15, lq = lane >> 4;

    f32x4 acc[4][4] = {};
    constexpr int nkt = 1408 >> 6;   // 22

    for (int kt = 0; kt < nkt; kt++) {
        int k0 = kbase + kt * 64;
#pragma unroll
        for (int j = 0; j < 4; j++) {
            int L = j * 256 + tid;
            int m = L >> 3, cp = L & 7, c = cp ^ (m & 7);
            int gr = row0 + m; if (gr >= M) gr = M - 1;
            async16(A + (size_t)gr * KA + k0 + c * 8, (void*)(As + L * 8));
            async16(B + (size_t)(col0 + m) * KA + k0 + c * 8, (void*)(Bs + L * 8));
        }
        __syncthreads();
#pragma unroll
        for (int kk = 0; kk < 2; kk++) {
            bf16x8 af[4], bfr[4];
            int cc = kk * 4 + lq;
#pragma unroll
            for (int i = 0; i < 4; i++) {
                int ra = wm + i * 16 + lm;
                af[i] = *(const bf16x8*)(As + ra * 64 + ((cc ^ (ra & 7)) * 8));
                int rb2 = wn + i * 16 + lm;
                bfr[i] = *(const bf16x8*)(Bs + rb2 * 64 + ((cc ^ (rb2 & 7)) * 8));
            }
#pragma unroll
            for (int mi = 0; mi < 4; mi++)
#pragma unroll
                for (int ni = 0; ni < 4; ni++)
                    acc[mi][ni] = __builtin_amdgcn_mfma_f32_16x16x32_bf16(af[mi], bfr[ni], acc[mi][ni], 0, 0, 0);
        }
        __syncthreads();
    }
#pragma unroll
    for (int mi = 0; mi < 4; mi++)
#pragma unroll
        for (int r = 0; r < 4; r++) {
            int cr = row0 + wm + mi * 16 + lq * 4 + r;
            if (cr >= M) continue;
            int t = lst ? lst[cr] : cr;
#pragma unroll
            for (int ni = 0; ni < 4; ni++) {
                int gc = col0 + wn + ni * 16 + lm;
                atomicAdd(&out[(size_t)t * H_ + gc], acc[mi][ni][r]);
            }
        }
}

// ---------------- launch ----------------
extern "C" void kernel_launch(void* const* d_in, const int* in_sizes, int n_in,
                              void* d_out, int out_size, void* d_ws, size_t ws_size,
                              hipStream_t stream) {
    const float* x     = (const float*)d_in[0];
    const float* gw    = (const float*)d_in[1];
    const float* gproj = (const float*)d_in[2];
    const float* uproj = (const float*)d_in[3];
    const float* dproj = (const float*)d_in[4];
    const float* sg    = (const float*)d_in[5];
    const float* su    = (const float*)d_in[6];
    const float* sd    = (const float*)d_in[7];
    float* out = (float*)d_out;

    char* w = (char*)d_ws;
    size_t off = 0;
    auto alloc = [&](size_t bytes) { void* p = w + off; off += (bytes + 255) & ~(size_t)255; return p; };
    bf16* wg_t   = (bf16*)alloc((size_t)E_ * F_ * H_ * 2);   // [E][F][H]
    bf16* wu_t   = (bf16*)alloc((size_t)E_ * F_ * H_ * 2);   // [E][F][H]
    bf16* wd_t   = (bf16*)alloc((size_t)E_ * H_ * F_ * 2);   // [E][H][F]
    bf16* sg_t   = (bf16*)alloc((size_t)SF_ * H_ * 2);       // [SF][H]
    bf16* su_t   = (bf16*)alloc((size_t)SF_ * H_ * 2);       // [SF][H]
    bf16* sd_t   = (bf16*)alloc((size_t)H_ * SF_ * 2);       // [H][SF]
    bf16* xb     = (bf16*)alloc((size_t)T_ * H_ * 2);        // [T][H]
    bf16* xA     = (bf16*)alloc((size_t)E_ * T_ * H_ * 2);   // [E][T][H] gathered
    bf16* act    = (bf16*)alloc((size_t)E_ * T_ * F_ * 2);   // [E][T][F] (w-scaled)
    bf16* act_sh = (bf16*)alloc((size_t)T_ * SF_ * 2);       // [T][SF]
    int*  cnt    = (int*)alloc(256);
    int*  list   = (int*)alloc((size_t)E_ * T_ * 4);
    float* wlist = (float*)alloc((size_t)E_ * T_ * 4);
    (void)ws_size; (void)in_sizes; (void)n_in; (void)out_size;

    hipMemsetAsync(cnt, 0, 256, stream);
    hipMemsetAsync(out, 0, (size_t)T_ * H_ * 4, stream);

    mega_transpose<<<21120, 256, 0, stream>>>(gproj, uproj, dproj, sg, su, sd,
                                              wg_t, wu_t, wd_t, sg_t, su_t, sd_t);
    gate_cvt_route<<<T_, 256, 0, stream>>>(x, gw, xb, cnt, list, wlist);
    gather_rows<<<dim3(T_, E_), 256, 0, stream>>>(xb, cnt, list, xA);

    gemm_gu<<<GU_GRID, 256, 0, stream>>>(xb, xA, sg_t, su_t, wg_t, wu_t,
                                         act_sh, act, cnt, wlist);
    gemm_down<<<DN_GRID, 256, 0, stream>>>(act_sh, sd_t, act, wd_t, out, cnt, list);
}